// Round 14
// baseline (177.286 us; speedup 1.0000x reference)
//
#include <hip/hip_runtime.h>
#include <math.h>

#define N 8192
#define D 128
#define NT 64                    // 128-wide tiles per dim
#define NBLK (NT * (NT + 1) / 2) // 2080

typedef __attribute__((ext_vector_type(8))) short bf8;   // 8 bf16 = 4 VGPRs
typedef __attribute__((ext_vector_type(4))) float f4;    // MFMA acc

__device__ __forceinline__ unsigned short bf16_rtne(float f) {
    unsigned u = __float_as_uint(f);
    u += 0x7FFF + ((u >> 16) & 1);
    return (unsigned short)(u >> 16);
}
__device__ __forceinline__ float bf16_tof(unsigned short h) {
    return __uint_as_float((unsigned)h << 16);
}

__device__ __forceinline__ void async_cp16(const void* g, void* l) {
    __builtin_amdgcn_global_load_lds(
        (const __attribute__((address_space(1))) unsigned*)g,
        (__attribute__((address_space(3))) unsigned*)l, 16, 0, 0);
}

// ---------------------------------------------------------------------------
// Kernel 1: normalize + 3-limb split, LDS-free. 512 blocks x 16 rows;
// 16 lanes/row x 8 elems. Also inits best-packs.
// ---------------------------------------------------------------------------
__global__ __launch_bounds__(256) void prep_kernel(
    const float* __restrict__ x, short* __restrict__ H,
    float* __restrict__ sq,
    unsigned long long* __restrict__ pos_pack,
    unsigned long long* __restrict__ neg_pack) {
    const int t = threadIdx.x;
    const int r = t >> 4, q = t & 15;
    const int row = blockIdx.x * 16 + r;

    if (t < 16) {
        pos_pack[blockIdx.x * 16 + t] = 0ULL;
        neg_pack[blockIdx.x * 16 + t] = ~0ULL;
    }

    const float* px = x + (size_t)row * D + q * 8;
    const float4 a = *(const float4*)px;
    const float4 bq = *(const float4*)(px + 4);
    float v[8] = {a.x, a.y, a.z, a.w, bq.x, bq.y, bq.z, bq.w};

    float s = 0.f;
#pragma unroll
    for (int i = 0; i < 8; ++i) s = fmaf(v[i], v[i], s);
    s += __shfl_xor(s, 1, 64);
    s += __shfl_xor(s, 2, 64);
    s += __shfl_xor(s, 4, 64);
    s += __shfl_xor(s, 8, 64);
    const float nrm = sqrtf(s);

    float t2 = 0.f;
#pragma unroll
    for (int i = 0; i < 8; ++i) {
        v[i] = v[i] / nrm;
        t2 = fmaf(v[i], v[i], t2);
    }
    t2 += __shfl_xor(t2, 1, 64);
    t2 += __shfl_xor(t2, 2, 64);
    t2 += __shfl_xor(t2, 4, 64);
    t2 += __shfl_xor(t2, 8, 64);
    if (q == 0) sq[row] = t2;

    const size_t gbase = (size_t)row * D + q * 8;
#pragma unroll
    for (int g = 0; g < 2; ++g) {
        short4 o1, o2, o3;
        short* p1 = (short*)&o1; short* p2 = (short*)&o2; short* p3 = (short*)&o3;
#pragma unroll
        for (int i = 0; i < 4; ++i) {
            const float n = v[g * 4 + i];
            const unsigned short h1 = bf16_rtne(n);
            const float r1 = n - bf16_tof(h1);
            const unsigned short h2 = bf16_rtne(r1);
            const float r2 = r1 - bf16_tof(h2);
            const unsigned short h3 = bf16_rtne(r2);
            p1[i] = (short)h1; p2[i] = (short)h2; p3[i] = (short)h3;
        }
        *(short4*)(H + gbase + g * 4)                     = o1;
        *(short4*)(H + (size_t)N * D + gbase + g * 4)     = o2;
        *(short4*)(H + (size_t)2 * N * D + gbase + g * 4) = o3;
    }
}

// ---------------------------------------------------------------------------
// Kernel 2: symmetric 128x128-tile Gram, 3-limb bf16 mfma_16x16x32.
// R14: 512 threads, wave owns 16 rows x 128 cols -> acc = 32 AGPRs (total
// regs/wave ~100-110 vs R13's ~176, the occupancy binder). Single-pass
// epilogue computes d2/vp/vn once, feeding I and J updates. Limb staging /
// product order identical to verified R13 (bit-exact).
// ---------------------------------------------------------------------------
__device__ __forceinline__ unsigned int fbits(float f) {
    union { float f; unsigned int u; } x; x.f = f; return x.u;
}
__device__ __forceinline__ unsigned long long pack_pos(float v, int j) {
    return ((unsigned long long)fbits(v) << 32) | (unsigned int)(8191 - j);
}
__device__ __forceinline__ unsigned long long pack_neg(float v, int j) {
    return ((unsigned long long)fbits(v) << 32) | (unsigned int)j;
}
__device__ __forceinline__ void red_max(float& v, int& j, int mask) {
    const float ov = __shfl_xor(v, mask, 64);
    const int   oj = __shfl_xor(j, mask, 64);
    if (ov > v || (ov == v && oj < j)) { v = ov; j = oj; }
}
__device__ __forceinline__ void red_min(float& v, int& j, int mask) {
    const float ov = __shfl_xor(v, mask, 64);
    const int   oj = __shfl_xor(j, mask, 64);
    if (ov < v || (ov == v && oj < j)) { v = ov; j = oj; }
}

__global__ __launch_bounds__(512) void miner_kernel(
    const short* __restrict__ H, const float* __restrict__ sq,
    const int* __restrict__ labels,
    unsigned long long* __restrict__ pos_pack,
    unsigned long long* __restrict__ neg_pack) {
    // A: [2 limb][128 smp][32 k] = 8192 shorts; B: [3 limb][128][32] = 12288.
    __shared__ __align__(16) short sT[20480];   // 40960 B

    const int t = threadIdx.x;
    const int w = t >> 6;       // 0..7: rows w*16..w*16+15
    const int l = t & 63;
    const int quad = l >> 4;
    const int l16 = l & 15;

    const int b = blockIdx.x;
    int bi = (int)((129.0f - sqrtf(16641.0f - 8.0f * (float)b)) * 0.5f);
    while (bi > 0 && (bi * NT - bi * (bi - 1) / 2) > b) --bi;
    while (((bi + 1) * NT - (bi + 1) * bi / 2) <= b) ++bi;
    const int bj = bi + (b - (bi * NT - bi * (bi - 1) / 2));
    const int I0 = bi * 128, J0 = bj * 128;
    const bool diag = (bi == bj);

    // staging: 5 x 16B per thread; p<2: A limb p; p>=2: B limb p-2.
    int gOff[5], lOff[5];
#pragma unroll
    for (int p = 0; p < 5; ++p) {
        const int side = (p >= 2);
        const int limb = side ? (p - 2) : p;
        const int smp = t >> 2;
        const int sub = t & 3;
        gOff[p] = limb * (N * D) + ((side ? J0 : I0) + smp) * D + sub * 8;
        lOff[p] = (side ? 8192 : 0) + (limb * 128 + smp) * 32 + sub * 8;
    }
    const int aGoff = 2 * (N * D) + (I0 + w * 16 + l16) * D + quad * 8;

    f4 acc[8];
#pragma unroll
    for (int ct = 0; ct < 8; ++ct) acc[ct] = (f4){0.f, 0.f, 0.f, 0.f};

    for (int q = 0; q < 4; ++q) {
        const int kc = q * 32;
        __syncthreads();
#pragma unroll
        for (int p = 0; p < 5; ++p)
            async_cp16(H + (size_t)(gOff[p] + kc), sT + lOff[p]);
        bf8 aG = *(const bf8*)(H + (size_t)(aGoff + kc));
        __syncthreads();

        const bf8 aF0 = *(const bf8*)&sT[(w * 16 + l16) * 32 + quad * 8];
        const bf8 aF1 = *(const bf8*)&sT[(128 + w * 16 + l16) * 32 + quad * 8];
#pragma unroll
        for (int ct = 0; ct < 8; ++ct) {
            const bf8 b0 = *(const bf8*)&sT[8192 + (ct * 16 + l16) * 32 + quad * 8];
            const bf8 b1 = *(const bf8*)&sT[8192 + ((128 + ct * 16 + l16)) * 32 + quad * 8];
            const bf8 b2 = *(const bf8*)&sT[8192 + ((256 + ct * 16 + l16)) * 32 + quad * 8];
            acc[ct] = __builtin_amdgcn_mfma_f32_16x16x32_bf16(aF0, b0, acc[ct], 0, 0, 0);
            acc[ct] = __builtin_amdgcn_mfma_f32_16x16x32_bf16(aF0, b1, acc[ct], 0, 0, 0);
            acc[ct] = __builtin_amdgcn_mfma_f32_16x16x32_bf16(aF0, b2, acc[ct], 0, 0, 0);
            acc[ct] = __builtin_amdgcn_mfma_f32_16x16x32_bf16(aF1, b0, acc[ct], 0, 0, 0);
            acc[ct] = __builtin_amdgcn_mfma_f32_16x16x32_bf16(aF1, b1, acc[ct], 0, 0, 0);
            acc[ct] = __builtin_amdgcn_mfma_f32_16x16x32_bf16(aG,  b0, acc[ct], 0, 0, 0);
        }
    }

    // ---- epilogue: sq/labels into reused sT ----
    __syncthreads();
    float* sqI = (float*)sT;              // bytes [0,512)
    float* sqJ = sqI + 128;               // [512,1024)
    int*   lbI = (int*)(sqJ + 128);       // [1024,1536)
    int*   lbJ = lbI + 128;               // [1536,2048)
    unsigned long long* scr =
        (unsigned long long*)((char*)sT + 2048);  // 16 KB: pos[1024], neg[1024]
    if (t < 128)      { sqI[t] = sq[I0 + t]; lbI[t] = labels[I0 + t]; }
    else if (t < 256) { sqJ[t - 128] = sq[J0 + t - 128];
                        lbJ[t - 128] = labels[J0 + t - 128]; }
    __syncthreads();

    const int lr0 = w * 16 + quad * 4;
    float si[4]; int li[4];
#pragma unroll
    for (int r = 0; r < 4; ++r) { si[r] = sqI[lr0 + r]; li[r] = lbI[lr0 + r]; }

    float bpvI[4], bnvI[4]; int bpjI[4], bnjI[4];
#pragma unroll
    for (int r = 0; r < 4; ++r) {
        bpvI[r] = -1.0f; bpjI[r] = 0; bnvI[r] = INFINITY; bnjI[r] = 0;
    }

    if (diag) {
#pragma unroll
        for (int ct = 0; ct < 8; ++ct) {
            const float sj = sqJ[ct * 16 + l16];
            const int lj = lbJ[ct * 16 + l16];
            const int col = J0 + ct * 16 + l16;
#pragma unroll
            for (int r = 0; r < 4; ++r) {
                const float d2 = fmaxf(si[r] + sj - 2.0f * acc[ct][r], 0.0f);
                const bool same = (li[r] == lj);
                const int grow = I0 + lr0 + r;
                const float vp = (same && grow != col) ? d2 : 0.0f;
                if (vp > bpvI[r]) { bpvI[r] = vp; bpjI[r] = col; }
                const float vn = same ? INFINITY : d2;
                if (vn < bnvI[r]) { bnvI[r] = vn; bnjI[r] = col; }
            }
        }
    } else {
#pragma unroll
        for (int ct = 0; ct < 8; ++ct) {
            const float sj = sqJ[ct * 16 + l16];
            const int lj = lbJ[ct * 16 + l16];
            const int col = J0 + ct * 16 + l16;
            float bpvJ = -1.0f, bnvJ = INFINITY; int bpjJ = 0, bnjJ = 0;
#pragma unroll
            for (int r = 0; r < 4; ++r) {
                const float d2 = fmaxf(si[r] + sj - 2.0f * acc[ct][r], 0.0f);
                const bool same = (li[r] == lj);
                const float vp = same ? d2 : 0.0f;      // no self off-diagonal
                const float vn = same ? INFINITY : d2;
                if (vp > bpvI[r]) { bpvI[r] = vp; bpjI[r] = col; }
                if (vn < bnvI[r]) { bnvI[r] = vn; bnjI[r] = col; }
                const int row = I0 + lr0 + r;
                if (vp > bpvJ) { bpvJ = vp; bpjJ = row; }
                if (vn < bnvJ) { bnvJ = vn; bnjJ = row; }
            }
            // reduce J over quad (rows within wave), write wave partial
            red_max(bpvJ, bpjJ, 16); red_max(bpvJ, bpjJ, 32);
            red_min(bnvJ, bnjJ, 16); red_min(bnvJ, bnjJ, 32);
            if (quad == 0) {
                scr[w * 128 + ct * 16 + l16]        = pack_pos(bpvJ, bpjJ);
                scr[1024 + w * 128 + ct * 16 + l16] = pack_neg(bnvJ, bnjJ);
            }
        }
    }

    // I-side butterfly over l16 lanes + commit
#pragma unroll
    for (int r = 0; r < 4; ++r) {
        red_max(bpvI[r], bpjI[r], 1); red_max(bpvI[r], bpjI[r], 2);
        red_max(bpvI[r], bpjI[r], 4); red_max(bpvI[r], bpjI[r], 8);
        red_min(bnvI[r], bnjI[r], 1); red_min(bnvI[r], bnjI[r], 2);
        red_min(bnvI[r], bnjI[r], 4); red_min(bnvI[r], bnjI[r], 8);
    }
    if (l16 == 0) {
#pragma unroll
        for (int r = 0; r < 4; ++r) {
            atomicMax(&pos_pack[I0 + lr0 + r], pack_pos(bpvI[r], bpjI[r]));
            atomicMin(&neg_pack[I0 + lr0 + r], pack_neg(bnvI[r], bnjI[r]));
        }
    }

    // J-side cross-wave merge + commit
    if (!diag) {
        __syncthreads();
        if (t < 128) {
            unsigned long long mp = 0ULL, mn = ~0ULL;
#pragma unroll
            for (int ww = 0; ww < 8; ++ww) {
                const unsigned long long p = scr[ww * 128 + t];
                const unsigned long long qq = scr[1024 + ww * 128 + t];
                if (p > mp) mp = p;
                if (qq < mn) mn = qq;
            }
            atomicMax(&pos_pack[J0 + t], mp);
            atomicMin(&neg_pack[J0 + t], mn);
        }
    }
}

// ---------------------------------------------------------------------------
// Kernel 3: finalize -> int32 outputs [anchor | pos | neg | keep].
// keep from pack sentinels (untouched = no candidate existed).
// ---------------------------------------------------------------------------
__global__ void finalize_kernel(const unsigned long long* __restrict__ pos_pack,
                                const unsigned long long* __restrict__ neg_pack,
                                int* __restrict__ out) {
    const int r = blockIdx.x * 256 + threadIdx.x;
    const unsigned long long pp = pos_pack[r];
    const unsigned long long np = neg_pack[r];
    out[r]         = r;
    out[N + r]     = 8191 - (int)(pp & 0xFFFFFFFFULL);
    out[2 * N + r] = (int)(np & 0xFFFFFFFFULL);
    out[3 * N + r] = (pp != 0ULL && np != ~0ULL) ? 1 : 0;
}

extern "C" void kernel_launch(void* const* d_in, const int* in_sizes, int n_in,
                              void* d_out, int out_size, void* d_ws, size_t ws_size,
                              hipStream_t stream) {
    const float* x      = (const float*)d_in[0];
    const int*   labels = (const int*)d_in[1];
    int* out = (int*)d_out;

    short* H = (short*)d_ws;                                // 3*N*D bf16 = 6 MB
    float* sq = (float*)(H + (size_t)3 * N * D);            // N floats
    unsigned long long* pos_pack =
        (unsigned long long*)(sq + N);                      // N u64
    unsigned long long* neg_pack = pos_pack + N;            // N u64

    prep_kernel<<<N / 16, 256, 0, stream>>>(x, H, sq, pos_pack, neg_pack);
    miner_kernel<<<NBLK, 512, 0, stream>>>(H, sq, labels, pos_pack, neg_pack);
    finalize_kernel<<<N / 256, 256, 0, stream>>>(pos_pack, neg_pack, out);
}